// Round 5
// baseline (263.730 us; speedup 1.0000x reference)
//
#include <hip/hip_runtime.h>

// ---------------------------------------------------------------------------
// GAT 3-layer forward, MI355X (gfx950)
// R12: GEMM latency/occupancy restructure (R11 post-mortem: A-traffic x2
//      regressed; occupancy must come from LDS+block size, not col-split).
//      * K-sliced B staging: 4 slices of 64k x NN cols = 32 KB LDS (NN=256)
//      * 256-thr blocks (4 waves x 16 rows = 64 rows) -> grid 782 > 256 CUs
//      * A read ONCE, streamed per-slice (2 cur + 2 prefetch fragments)
//      * __launch_bounds__(256,4): target 4 waves/SIMD, ~16 waves/CU (2x R10)
//      agg kernels unchanged (R9-verified). fill fused into gemm1 grid.
// ---------------------------------------------------------------------------

typedef __attribute__((ext_vector_type(8))) __bf16 bf16x8;
typedef __attribute__((ext_vector_type(4))) float f32x4;
typedef _Float16 f16x8 __attribute__((ext_vector_type(8)));
typedef _Float16 f16x4 __attribute__((ext_vector_type(4)));

#define NEG_SLOPE 0.2f
#define WELL 40   // ELL row width; P(deg>40) ~ 1e-15 for E/N=6.4 Poisson

__device__ __forceinline__ unsigned short f2b_rne(float f) {
    unsigned int u = __float_as_uint(f);
    u += 0x7FFFu + ((u >> 16) & 1u);
    return (unsigned short)(u >> 16);
}
__device__ __forceinline__ unsigned short f2h(float f) {
    _Float16 h = (_Float16)f;
    unsigned short s;
    __builtin_memcpy(&s, &h, 2);
    return s;
}
__device__ __forceinline__ bf16x8 cvt8(const float* f) {
    unsigned short r[8];
#pragma unroll
    for (int j = 0; j < 8; j++) r[j] = f2b_rne(f[j]);
    bf16x8 v;
    __builtin_memcpy(&v, r, 16);
    return v;
}
__device__ __forceinline__ float lrelu(float e) {
    return e >= 0.f ? e : NEG_SLOPE * e;
}

// ---- init: zero cnt + all W -> Wt [Nout,256] bf16 transposed --------------
__global__ __launch_bounds__(256) void k_init(const float* __restrict__ W1,
                                              const float* __restrict__ W2,
                                              const float* __restrict__ W3,
                                              unsigned short* __restrict__ W1t,
                                              unsigned short* __restrict__ W2t,
                                              unsigned short* __restrict__ W3t,
                                              int* __restrict__ cnt, int n) {
    int t = blockIdx.x * blockDim.x + threadIdx.x;
    if (t < n) cnt[t] = 0;
    const float* W;
    unsigned short* Wt;
    int Nout, idx = t;
    if (idx < 65536)        { W = W1; Wt = W1t; Nout = 256; }
    else if (idx < 131072)  { W = W2; Wt = W2t; Nout = 256; idx -= 65536; }
    else if (idx < 147456)  { W = W3; Wt = W3t; Nout = 64;  idx -= 131072; }
    else return;
    int k = idx / Nout;
    int c = idx - k * Nout;
    Wt[(size_t)c * 256 + k] = f2b_rne(W[idx]);
}

// ---- GEMM: h16[M,NN] f16 = A[M,256] @ Wt[NN,256]^T, fused als/ald ---------
// B staged in 4 K-slices of 64k (Bs[NN][64] = NN*128 B), XOR chunk swizzle
// (chunk p of row n holds global chunk p^(n&7) within the 64k slice).
// 4 waves x 16 rows = 64 rows/block; A streamed per-slice with 1-slice
// prefetch; per-slice sync pair; cross-block overlap hides stage latency.
// FILL: blocks >= gblocks do the ELL adjacency fill (grid-stride over E).
template <int NT, bool AF32, bool FILL>
__global__ __launch_bounds__(256, 4) void k_gemm(const void* __restrict__ Av,
                                              const __bf16* __restrict__ Bt,
                                              unsigned short* __restrict__ h16,
                                              float* __restrict__ als,
                                              float* __restrict__ ald,
                                              const float* __restrict__ a_s,
                                              const float* __restrict__ a_d,
                                              int M, int H,
                                              const int* __restrict__ esrc,
                                              const int* __restrict__ edst,
                                              int* __restrict__ cnt,
                                              int* __restrict__ ell,
                                              int E, int gblocks) {
    constexpr int NN = NT * 16;
    __shared__ __align__(16) __bf16 Bs[NN][64];

    if (FILL && (int)blockIdx.x >= gblocks) {
        int t = ((int)blockIdx.x - gblocks) * (int)blockDim.x + (int)threadIdx.x;
        int stride = ((int)gridDim.x - gblocks) * (int)blockDim.x;
        for (; t < E; t += stride) {
            int d = edst[t];
            int pos = atomicAdd(&cnt[d], 1);
            if (pos < WELL) ell[(size_t)d * WELL + pos] = esrc[t];
        }
        return;
    }

    const int tid = threadIdx.x;
    const int lane = tid & 63;
    const int w = tid >> 6;          // 4 waves
    const int i = lane & 15;
    const int quad = lane >> 4;
    const int m0 = (int)blockIdx.x * 64;

    // stage K-slice q: rows 0..NN, k = q*64..q*64+64, inverse-swizzled source
    const int st_r = (lane >> 3);        // row within 8-row group
    const int st_p = lane & 7;           // 16B chunk within 128B row
    auto stage = [&](int q) {
#pragma unroll
        for (int t = 0; t < NN / 32; t++) {
            int rowbase = t * 32 + w * 8;        // wave-uniform
            int r = rowbase + st_r;
            int c = st_p ^ (r & 7);
            const __bf16* gp = Bt + (size_t)r * 256 + q * 64 + c * 8;
            __builtin_amdgcn_global_load_lds(
                (const __attribute__((address_space(1))) void*)gp,
                (__attribute__((address_space(3))) void*)&Bs[rowbase][0],
                16, 0, 0);
        }
    };

    int ra = m0 + w * 16 + i;
    if (ra >= M) ra = M - 1;

    f32x4 acc[NT] = {};
    bf16x8 afc[2];   // current-slice A fragments (k-chunks kc2=0,1)

    // prologue: stage slice 0 + issue A slice 0
    stage(0);
    float t0[2][8];
    if (AF32) {
        const float* pa = (const float*)Av + (size_t)ra * 256;
#pragma unroll
        for (int kc2 = 0; kc2 < 2; kc2++) {
            int koff = kc2 * 32 + quad * 8;
            *(float4*)&t0[kc2][0] = *(const float4*)(pa + koff);
            *(float4*)&t0[kc2][4] = *(const float4*)(pa + koff + 4);
        }
    } else {
        const __bf16* pa = (const __bf16*)Av + (size_t)ra * 256;
        afc[0] = *(const bf16x8*)(pa + quad * 8);
        afc[1] = *(const bf16x8*)(pa + 32 + quad * 8);
    }
    __syncthreads();
    if (AF32) {
        afc[0] = cvt8(t0[0]);
        afc[1] = cvt8(t0[1]);
    }

#pragma unroll
    for (int q = 0; q < 4; q++) {
        float tn[2][8];
        bf16x8 afn[2];
        // prefetch A slice q+1 (lands under this slice's MFMA)
        if (q < 3) {
            if (AF32) {
                const float* pa = (const float*)Av + (size_t)ra * 256 + (q + 1) * 64;
#pragma unroll
                for (int kc2 = 0; kc2 < 2; kc2++) {
                    int koff = kc2 * 32 + quad * 8;
                    *(float4*)&tn[kc2][0] = *(const float4*)(pa + koff);
                    *(float4*)&tn[kc2][4] = *(const float4*)(pa + koff + 4);
                }
            } else {
                const __bf16* pa = (const __bf16*)Av + (size_t)ra * 256 + (q + 1) * 64;
                afn[0] = *(const bf16x8*)(pa + quad * 8);
                afn[1] = *(const bf16x8*)(pa + 32 + quad * 8);
            }
        }
        // MFMA over this slice
#pragma unroll
        for (int kc2 = 0; kc2 < 2; kc2++) {
            const int c = kc2 * 4 + quad;
#pragma unroll
            for (int nt = 0; nt < NT; nt++) {
                const int n = nt * 16 + i;
                const int p = c ^ (n & 7);
                bf16x8 bfv = *(const bf16x8*)&Bs[n][p * 8];
                acc[nt] = __builtin_amdgcn_mfma_f32_16x16x32_bf16(
                    afc[kc2], bfv, acc[nt], 0, 0, 0);
            }
        }
        if (q < 3) {
            if (AF32) {
                afc[0] = cvt8(tn[0]);
                afc[1] = cvt8(tn[1]);
            } else {
                afc[0] = afn[0];
                afc[1] = afn[1];
            }
            __syncthreads();     // all waves done reading slice q
            stage(q + 1);
            __syncthreads();     // slice q+1 resident
        }
    }

    // ---- epilogue: C/D map col=lane&15, row=quad*4+reg --------------------
    float asv[NT], adv[NT];
#pragma unroll
    for (int nt = 0; nt < NT; nt++) {
        asv[nt] = a_s[(nt >> 2) * 64 + (nt & 3) * 16 + i];
        adv[nt] = a_d[(nt >> 2) * 64 + (nt & 3) * 16 + i];
    }

#pragma unroll
    for (int r = 0; r < 4; r++) {
        int row = m0 + w * 16 + quad * 4 + r;
        bool ok = row < M;
#pragma unroll
        for (int nt = 0; nt < NT; nt++) {
            if (ok) h16[(size_t)row * NN + nt * 16 + i] = f2h(acc[nt][r]);
        }
#pragma unroll
        for (int g = 0; g < (NT + 3) / 4; g++) {
            float ps = 0.f, pd = 0.f;
#pragma unroll
            for (int j = 0; j < 4 && g * 4 + j < NT; j++) {
                float v = acc[g * 4 + j][r];
                ps += v * asv[g * 4 + j];
                pd += v * adv[g * 4 + j];
            }
#pragma unroll
            for (int off = 1; off <= 8; off <<= 1) {
                ps += __shfl_xor(ps, off, 64);
                pd += __shfl_xor(pd, off, 64);
            }
            if (ok && i == 0) {
                als[(size_t)row * H + g] = ps;
                ald[(size_t)row * H + g] = pd;
            }
        }
    }
}

// ---- aggregation, H=4 C=64: 2 nodes/wave, 32 lanes/node, 8 ch/lane --------
__global__ __launch_bounds__(256) void k_agg4(const unsigned short* __restrict__ h16,
                                              const float* __restrict__ als,
                                              const float* __restrict__ ald,
                                              const int* __restrict__ cnt,
                                              const int* __restrict__ ell,
                                              const float* __restrict__ bias,
                                              unsigned short* __restrict__ xout,
                                              int n) {
    int gw = (blockIdx.x * blockDim.x + threadIdx.x) >> 6;
    int lane = threadIdx.x & 63;
    int wid = gw * 2 + (lane >> 5);
    if (wid >= n) return;
    int l = lane & 31;
    int head = l >> 3;       // 8 lanes per head
    int ch = l * 8;          // 8 f16 channels per lane
    int base = lane & 32;    // node-group base lane for shfl

    int deg = min(cnt[wid], WELL);
    const int* row = ell + (size_t)wid * WELL;
    int myid = (l < deg) ? row[l] : 0;   // cooperative id prefetch, slots 0..31

    float aldv = ald[wid * 4 + head];
    float p = __expf(fminf(lrelu(als[wid * 4 + head] + aldv), 60.f));
    float ssum = p;
    float a[8];
    {
        f16x8 h0 = *(const f16x8*)&h16[(size_t)wid * 256 + ch];
#pragma unroll
        for (int j = 0; j < 8; j++) a[j] = p * (float)h0[j];
    }

    int jmax = min(deg, 32);
    int dm1 = deg - 1;
    for (int j = 0; j < jmax; j += 4) {
        int s0 = __shfl(myid, base + min(j, dm1));
        int s1 = __shfl(myid, base + min(j + 1, dm1));
        int s2 = __shfl(myid, base + min(j + 2, dm1));
        int s3 = __shfl(myid, base + min(j + 3, dm1));
        float e0 = als[s0 * 4 + head];
        float e1 = als[s1 * 4 + head];
        float e2 = als[s2 * 4 + head];
        float e3 = als[s3 * 4 + head];
        f16x8 v0 = *(const f16x8*)&h16[(size_t)s0 * 256 + ch];
        f16x8 v1 = *(const f16x8*)&h16[(size_t)s1 * 256 + ch];
        f16x8 v2 = *(const f16x8*)&h16[(size_t)s2 * 256 + ch];
        f16x8 v3 = *(const f16x8*)&h16[(size_t)s3 * 256 + ch];
        float p0 = __expf(fminf(lrelu(e0 + aldv), 60.f));
        float p1 = (j + 1 < deg) ? __expf(fminf(lrelu(e1 + aldv), 60.f)) : 0.f;
        float p2 = (j + 2 < deg) ? __expf(fminf(lrelu(e2 + aldv), 60.f)) : 0.f;
        float p3 = (j + 3 < deg) ? __expf(fminf(lrelu(e3 + aldv), 60.f)) : 0.f;
        ssum += (p0 + p1) + (p2 + p3);
#pragma unroll
        for (int k = 0; k < 8; k++) {
            a[k] += (p0 * (float)v0[k] + p1 * (float)v1[k]) +
                    (p2 * (float)v2[k] + p3 * (float)v3[k]);
        }
    }
    // rare tail: deg > 32
    for (int j = 32; j < deg; ++j) {
        int s0 = row[j];
        float p0 = __expf(fminf(lrelu(als[s0 * 4 + head] + aldv), 60.f));
        f16x8 v0 = *(const f16x8*)&h16[(size_t)s0 * 256 + ch];
        ssum += p0;
#pragma unroll
        for (int k = 0; k < 8; k++) a[k] += p0 * (float)v0[k];
    }

    float inv = 1.f / (ssum + 1e-16f);
    float bb[8];
    *(float4*)&bb[0] = *(const float4*)&bias[ch];
    *(float4*)&bb[4] = *(const float4*)&bias[ch + 4];
    unsigned short o[8];
#pragma unroll
    for (int k = 0; k < 8; k++) {
        float r = a[k] * inv + bb[k];
        r = r > 0.f ? r : expm1f(r);
        o[k] = f2b_rne(r);
    }
    *(int4*)&xout[(size_t)wid * 256 + ch] = *(const int4*)&o[0];
}

// ---- aggregation, H=1 C=64, final: 8 lanes/node, 8 ch/lane, f32 out -------
__global__ __launch_bounds__(256) void k_agg1(const unsigned short* __restrict__ h16,
                                              const float* __restrict__ als,
                                              const float* __restrict__ ald,
                                              const int* __restrict__ cnt,
                                              const int* __restrict__ ell,
                                              const float* __restrict__ bias,
                                              float* __restrict__ out, int n) {
    int gw = (blockIdx.x * blockDim.x + threadIdx.x) >> 6;
    int lane = threadIdx.x & 63;
    int wid = gw * 8 + (lane >> 3);
    if (wid >= n) return;
    int l = lane & 7;
    int ch = l * 8;
    int base = lane & 56;

    int deg = min(cnt[wid], WELL);
    const int* row = ell + (size_t)wid * WELL;
    int myid = (l < deg) ? row[l] : 0;

    float aldv = ald[wid];
    float p = __expf(fminf(lrelu(als[wid] + aldv), 60.f));
    float ssum = p;
    float a[8];
    {
        f16x8 hv = *(const f16x8*)&h16[(size_t)wid * 64 + ch];
#pragma unroll
        for (int k = 0; k < 8; k++) a[k] = p * (float)hv[k];
    }

    int dm1 = deg - 1;
    for (int j = 0; j < deg; j += 4) {
        int i0 = min(j, dm1), i1 = min(j + 1, dm1);
        int i2 = min(j + 2, dm1), i3 = min(j + 3, dm1);
        int s0, s1, s2, s3;
        if (j < 8) {
            s0 = __shfl(myid, base + i0);
            s1 = __shfl(myid, base + i1);
            s2 = __shfl(myid, base + i2);
            s3 = __shfl(myid, base + i3);
        } else {
            s0 = row[i0]; s1 = row[i1]; s2 = row[i2]; s3 = row[i3];
        }
        float e0 = als[s0], e1 = als[s1], e2 = als[s2], e3 = als[s3];
        f16x8 v0 = *(const f16x8*)&h16[(size_t)s0 * 64 + ch];
        f16x8 v1 = *(const f16x8*)&h16[(size_t)s1 * 64 + ch];
        f16x8 v2 = *(const f16x8*)&h16[(size_t)s2 * 64 + ch];
        f16x8 v3 = *(const f16x8*)&h16[(size_t)s3 * 64 + ch];
        float p0 = __expf(fminf(lrelu(e0 + aldv), 60.f));
        float p1 = (j + 1 < deg) ? __expf(fminf(lrelu(e1 + aldv), 60.f)) : 0.f;
        float p2 = (j + 2 < deg) ? __expf(fminf(lrelu(e2 + aldv), 60.f)) : 0.f;
        float p3 = (j + 3 < deg) ? __expf(fminf(lrelu(e3 + aldv), 60.f)) : 0.f;
        ssum += (p0 + p1) + (p2 + p3);
#pragma unroll
        for (int k = 0; k < 8; k++)
            a[k] += (p0 * (float)v0[k] + p1 * (float)v1[k]) +
                    (p2 * (float)v2[k] + p3 * (float)v3[k]);
    }

    float inv = 1.f / (ssum + 1e-16f);
    float bb[8];
    *(float4*)&bb[0] = *(const float4*)&bias[ch];
    *(float4*)&bb[4] = *(const float4*)&bias[ch + 4];
    float r[8];
#pragma unroll
    for (int k = 0; k < 8; k++) r[k] = a[k] * inv + bb[k];
    *(float4*)&out[(size_t)wid * 64 + ch] = *(const float4*)&r[0];
    *(float4*)&out[(size_t)wid * 64 + ch + 4] = *(const float4*)&r[4];
}

// ---------------------------------------------------------------------------
extern "C" void kernel_launch(void* const* d_in, const int* in_sizes, int n_in,
                              void* d_out, int out_size, void* d_ws, size_t ws_size,
                              hipStream_t stream) {
    const float* x   = (const float*)d_in[0];
    const int*   ei  = (const int*)d_in[1];
    const float* W1  = (const float*)d_in[2];
    const float* as1 = (const float*)d_in[3];
    const float* ad1 = (const float*)d_in[4];
    const float* b1  = (const float*)d_in[5];
    const float* W2  = (const float*)d_in[6];
    const float* as2 = (const float*)d_in[7];
    const float* ad2 = (const float*)d_in[8];
    const float* b2  = (const float*)d_in[9];
    const float* W3  = (const float*)d_in[10];
    const float* as3 = (const float*)d_in[11];
    const float* ad3 = (const float*)d_in[12];
    const float* b3  = (const float*)d_in[13];

    const int N = in_sizes[0] / 256;   // 50000
    const int E = in_sizes[1] / 2;     // 320000

    size_t off = 0;
    auto alloc = [&](size_t bytes) -> void* {
        void* p = (char*)d_ws + off;
        off += (bytes + 255) & ~(size_t)255;
        return p;
    };
    unsigned short* xb  = (unsigned short*)alloc((size_t)N * 256 * 2);
    unsigned short* W1t = (unsigned short*)alloc((size_t)256 * 256 * 2);
    unsigned short* W2t = (unsigned short*)alloc((size_t)256 * 256 * 2);
    unsigned short* W3t = (unsigned short*)alloc((size_t)64 * 256 * 2);
    unsigned short* h16 = (unsigned short*)alloc((size_t)N * 256 * 2);
    float* als = (float*)alloc((size_t)N * 4 * 4);
    float* ald = (float*)alloc((size_t)N * 4 * 4);
    int* cnt   = (int*)alloc((size_t)N * 4);
    int* ell   = (int*)alloc((size_t)N * WELL * 4);

    const int T = 256;
    const int agg4_blocks = (N + 7) / 8;    // 2 nodes/wave, 4 waves/block
    const int agg1_blocks = (N + 31) / 32;  // 8 nodes/wave, 4 waves/block
    const int mtiles = (N + 63) / 64;       // 782 (64 rows/block)

    // init: zero cnt + W conversions (one launch)
    k_init<<<dim3(576), T, 0, stream>>>(W1, W2, W3, W1t, W2t, W3t, cnt, N);

    // layer 1 GEMM (A = x f32) + 60 fill blocks appended
    k_gemm<16, true, true><<<dim3(mtiles + 60), T, 0, stream>>>(
        x, (const __bf16*)W1t, h16, als, ald, as1, ad1, N, 4,
        ei, ei + E, cnt, ell, E, mtiles);
    k_agg4<<<dim3(agg4_blocks), T, 0, stream>>>(h16, als, ald, cnt, ell, b1, xb, N);

    // layer 2 (A = xb bf16)
    k_gemm<16, false, false><<<dim3(mtiles), T, 0, stream>>>(
        xb, (const __bf16*)W2t, h16, als, ald, as2, ad2, N, 4,
        nullptr, nullptr, nullptr, nullptr, 0, mtiles);
    k_agg4<<<dim3(agg4_blocks), T, 0, stream>>>(h16, als, ald, cnt, ell, b2, xb, N);

    // layer 3 (H=1, C=64)
    k_gemm<4, false, false><<<dim3(mtiles), T, 0, stream>>>(
        xb, (const __bf16*)W3t, h16, als, ald, as3, ad3, N, 1,
        nullptr, nullptr, nullptr, nullptr, 0, mtiles);
    k_agg1<<<dim3(agg1_blocks), T, 0, stream>>>(h16, als, ald, cnt, ell, b3,
                                                (float*)d_out, N);
}

// Round 7
// 256.171 us; speedup vs baseline: 1.0295x; 1.0295x over previous
//
#include <hip/hip_runtime.h>

// ---------------------------------------------------------------------------
// GAT 3-layer forward, MI355X (gfx950)
// R13b: resubmit of R13 (container infra failure x2, no counters).
//      GEMM reverted to R10b exactly (verified best: 44us gemm1; R11/R12
//      occupancy restructures both regressed — gemm is pinned at
//      traffic/1.8TB/s regardless of occupancy/LDS structure).
//      agg4/agg1: software-pipelined gathers (T14) — 4-edge groups double-
//      buffered, group g+1's h16/als loads issued before group g's math.
//      Named A/B buffers, 2-unrolled loop, accumulation order preserved.
// ---------------------------------------------------------------------------

typedef __attribute__((ext_vector_type(8))) __bf16 bf16x8;
typedef __attribute__((ext_vector_type(4))) float f32x4;
typedef _Float16 f16x8 __attribute__((ext_vector_type(8)));
typedef _Float16 f16x4 __attribute__((ext_vector_type(4)));

#define NEG_SLOPE 0.2f
#define WELL 40   // ELL row width; P(deg>40) ~ 1e-15 for E/N=6.4 Poisson

__device__ __forceinline__ unsigned short f2b_rne(float f) {
    unsigned int u = __float_as_uint(f);
    u += 0x7FFFu + ((u >> 16) & 1u);
    return (unsigned short)(u >> 16);
}
__device__ __forceinline__ unsigned short f2h(float f) {
    _Float16 h = (_Float16)f;
    unsigned short s;
    __builtin_memcpy(&s, &h, 2);
    return s;
}
__device__ __forceinline__ bf16x8 cvt8(const float* f) {
    unsigned short r[8];
#pragma unroll
    for (int j = 0; j < 8; j++) r[j] = f2b_rne(f[j]);
    bf16x8 v;
    __builtin_memcpy(&v, r, 16);
    return v;
}
__device__ __forceinline__ float lrelu(float e) {
    return e >= 0.f ? e : NEG_SLOPE * e;
}

// ---- init: zero cnt + all W -> Wt [Nout,256] bf16 transposed --------------
__global__ __launch_bounds__(256) void k_init(const float* __restrict__ W1,
                                              const float* __restrict__ W2,
                                              const float* __restrict__ W3,
                                              unsigned short* __restrict__ W1t,
                                              unsigned short* __restrict__ W2t,
                                              unsigned short* __restrict__ W3t,
                                              int* __restrict__ cnt, int n) {
    int t = blockIdx.x * blockDim.x + threadIdx.x;
    if (t < n) cnt[t] = 0;
    const float* W;
    unsigned short* Wt;
    int Nout, idx = t;
    if (idx < 65536)        { W = W1; Wt = W1t; Nout = 256; }
    else if (idx < 131072)  { W = W2; Wt = W2t; Nout = 256; idx -= 65536; }
    else if (idx < 147456)  { W = W3; Wt = W3t; Nout = 64;  idx -= 131072; }
    else return;
    int k = idx / Nout;
    int c = idx - k * Nout;
    Wt[(size_t)c * 256 + k] = f2b_rne(W[idx]);
}

// ---- GEMM (R10b): h16[M,NT*16] f16 = A[M,256] @ Wt[NT*16,256]^T -----------
// Whole B-slab in LDS (NT*16 x 256 bf16), XOR chunk swizzle, staged once.
// Each wave: 32 rows, whole K in VGPRs, NT*16 cols, barrier-free K-loop.
// A loads issued AFTER the staging barrier. 512 thr = 8 waves = 256 rows.
template <int NT, bool AF32, bool FILL>
__global__ __launch_bounds__(512) void k_gemm(const void* __restrict__ Av,
                                              const __bf16* __restrict__ Bt,
                                              unsigned short* __restrict__ h16,
                                              float* __restrict__ als,
                                              float* __restrict__ ald,
                                              const float* __restrict__ a_s,
                                              const float* __restrict__ a_d,
                                              int M, int H,
                                              const int* __restrict__ esrc,
                                              const int* __restrict__ edst,
                                              int* __restrict__ cnt,
                                              int* __restrict__ ell,
                                              int E, int mtiles) {
    constexpr int NN = NT * 16;
    __shared__ __align__(16) __bf16 Bs[NN][256];

    if (FILL && (int)blockIdx.x >= mtiles) {
        int t = ((int)blockIdx.x - mtiles) * (int)blockDim.x + (int)threadIdx.x;
        int stride = ((int)gridDim.x - mtiles) * (int)blockDim.x;
        for (; t < E; t += stride) {
            int d = edst[t];
            int pos = atomicAdd(&cnt[d], 1);
            if (pos < WELL) ell[(size_t)d * WELL + pos] = esrc[t];
        }
        return;
    }

    const int tid = threadIdx.x;
    const int lane = tid & 63;
    const int w = tid >> 6;          // 8 waves
    const int i = lane & 15;
    const int quad = lane >> 4;
    const int m0 = blockIdx.x * 256;

    // ---- stage B slab once; chunk p of row n holds global chunk p^(n&7) ---
    {
        int nl = lane >> 5;          // 0..1
        int p = lane & 31;
#pragma unroll
        for (int t = 0; t < NN / 16; t++) {
            int n = t * 16 + w * 2 + nl;
            int g = p ^ (n & 7);
            const __bf16* gp = Bt + (size_t)n * 256 + g * 8;
            __builtin_amdgcn_global_load_lds(
                (const __attribute__((address_space(1))) void*)gp,
                (__attribute__((address_space(3))) void*)&Bs[t * 16 + w * 2][0],
                16, 0, 0);
        }
    }

    int ra = m0 + w * 32 + i;
    int rb = ra + 16;
    if (ra >= M) ra = M - 1;
    if (rb >= M) rb = M - 1;

    f32x4 acc[2][NT] = {};
    bf16x8 afrag[2][8];   // [strip][kc]

    __syncthreads();   // drains ONLY B staging; A loads issued below

    if (AF32) {
        const float* pa = (const float*)Av + (size_t)ra * 256;
        const float* pb = (const float*)Av + (size_t)rb * 256;
        float tmp[2][4][8];
        // half 0 loads: K 0..127
#pragma unroll
        for (int k4 = 0; k4 < 4; k4++) {
            int koff = k4 * 32 + quad * 8;
            *(float4*)&tmp[0][k4][0] = *(const float4*)(pa + koff);
            *(float4*)&tmp[0][k4][4] = *(const float4*)(pa + koff + 4);
            *(float4*)&tmp[1][k4][0] = *(const float4*)(pb + koff);
            *(float4*)&tmp[1][k4][4] = *(const float4*)(pb + koff + 4);
        }
#pragma unroll
        for (int k4 = 0; k4 < 4; k4++) {
            afrag[0][k4] = cvt8(tmp[0][k4]);
            afrag[1][k4] = cvt8(tmp[1][k4]);
        }
        // half 1 loads (reuse tmp) in flight while MFMA kc 0..3 runs
#pragma unroll
        for (int k4 = 0; k4 < 4; k4++) {
            int koff = (4 + k4) * 32 + quad * 8;
            *(float4*)&tmp[0][k4][0] = *(const float4*)(pa + koff);
            *(float4*)&tmp[0][k4][4] = *(const float4*)(pa + koff + 4);
            *(float4*)&tmp[1][k4][0] = *(const float4*)(pb + koff);
            *(float4*)&tmp[1][k4][4] = *(const float4*)(pb + koff + 4);
        }
#pragma unroll
        for (int kc = 0; kc < 4; kc++) {
            const int c = kc * 4 + quad;
#pragma unroll
            for (int nt = 0; nt < NT; nt++) {
                const int n = nt * 16 + i;
                const int p = c ^ (n & 7);
                bf16x8 bfv = *(const bf16x8*)&Bs[n][p * 8];
                acc[0][nt] = __builtin_amdgcn_mfma_f32_16x16x32_bf16(
                    afrag[0][kc], bfv, acc[0][nt], 0, 0, 0);
                acc[1][nt] = __builtin_amdgcn_mfma_f32_16x16x32_bf16(
                    afrag[1][kc], bfv, acc[1][nt], 0, 0, 0);
            }
        }
#pragma unroll
        for (int k4 = 0; k4 < 4; k4++) {
            afrag[0][4 + k4] = cvt8(tmp[0][k4]);
            afrag[1][4 + k4] = cvt8(tmp[1][k4]);
        }
#pragma unroll
        for (int kc = 4; kc < 8; kc++) {
            const int c = kc * 4 + quad;
#pragma unroll
            for (int nt = 0; nt < NT; nt++) {
                const int n = nt * 16 + i;
                const int p = c ^ (n & 7);
                bf16x8 bfv = *(const bf16x8*)&Bs[n][p * 8];
                acc[0][nt] = __builtin_amdgcn_mfma_f32_16x16x32_bf16(
                    afrag[0][kc], bfv, acc[0][nt], 0, 0, 0);
                acc[1][nt] = __builtin_amdgcn_mfma_f32_16x16x32_bf16(
                    afrag[1][kc], bfv, acc[1][nt], 0, 0, 0);
            }
        }
    } else {
        const __bf16* pa = (const __bf16*)Av + (size_t)ra * 256;
        const __bf16* pb = (const __bf16*)Av + (size_t)rb * 256;
#pragma unroll
        for (int kc = 0; kc < 8; kc++) {
            int koff = kc * 32 + quad * 8;
            afrag[0][kc] = *(const bf16x8*)(pa + koff);
            afrag[1][kc] = *(const bf16x8*)(pb + koff);
        }
#pragma unroll
        for (int kc = 0; kc < 8; kc++) {
            const int c = kc * 4 + quad;
#pragma unroll
            for (int nt = 0; nt < NT; nt++) {
                const int n = nt * 16 + i;
                const int p = c ^ (n & 7);
                bf16x8 bfv = *(const bf16x8*)&Bs[n][p * 8];
                acc[0][nt] = __builtin_amdgcn_mfma_f32_16x16x32_bf16(
                    afrag[0][kc], bfv, acc[0][nt], 0, 0, 0);
                acc[1][nt] = __builtin_amdgcn_mfma_f32_16x16x32_bf16(
                    afrag[1][kc], bfv, acc[1][nt], 0, 0, 0);
            }
        }
    }

    // ---- epilogue: C/D map col=lane&15, row=quad*4+reg --------------------
    float asv[NT], adv[NT];
#pragma unroll
    for (int nt = 0; nt < NT; nt++) {
        asv[nt] = a_s[(nt / 4) * 64 + (nt & 3) * 16 + i];
        adv[nt] = a_d[(nt / 4) * 64 + (nt & 3) * 16 + i];
    }

#pragma unroll
    for (int mt = 0; mt < 2; mt++) {
#pragma unroll
        for (int r = 0; r < 4; r++) {
            int row = m0 + w * 32 + mt * 16 + quad * 4 + r;
            bool ok = row < M;
#pragma unroll
            for (int nt = 0; nt < NT; nt++) {
                if (ok) h16[(size_t)row * NN + nt * 16 + i] = f2h(acc[mt][nt][r]);
            }
#pragma unroll
            for (int g = 0; g < (NT + 3) / 4; g++) {
                float ps = 0.f, pd = 0.f;
#pragma unroll
                for (int j = 0; j < 4 && g * 4 + j < NT; j++) {
                    float v = acc[mt][g * 4 + j][r];
                    ps += v * asv[g * 4 + j];
                    pd += v * adv[g * 4 + j];
                }
#pragma unroll
                for (int off = 1; off <= 8; off <<= 1) {
                    ps += __shfl_xor(ps, off, 64);
                    pd += __shfl_xor(pd, off, 64);
                }
                if (ok && i == 0) {
                    als[(size_t)row * H + g] = ps;
                    ald[(size_t)row * H + g] = pd;
                }
            }
        }
    }
}

// ---- aggregation, H=4 C=64: 2 nodes/wave, 32 lanes/node, 8 ch/lane --------
// Pipelined: group g+1's h16/als gathers issued before group g's math.
#define LOADG4(S0, S1, S2, S3, E0, E1, E2, E3, V0, V1, V2, V3, g)          \
    {                                                                      \
        int _j = (g) * 4;                                                  \
        S0 = __shfl(myid, base + min(_j, dm1));                            \
        S1 = __shfl(myid, base + min(_j + 1, dm1));                        \
        S2 = __shfl(myid, base + min(_j + 2, dm1));                        \
        S3 = __shfl(myid, base + min(_j + 3, dm1));                        \
        E0 = als[S0 * 4 + head];                                           \
        E1 = als[S1 * 4 + head];                                           \
        E2 = als[S2 * 4 + head];                                           \
        E3 = als[S3 * 4 + head];                                           \
        V0 = *(const f16x8*)&h16[(size_t)S0 * 256 + ch];                   \
        V1 = *(const f16x8*)&h16[(size_t)S1 * 256 + ch];                   \
        V2 = *(const f16x8*)&h16[(size_t)S2 * 256 + ch];                   \
        V3 = *(const f16x8*)&h16[(size_t)S3 * 256 + ch];                   \
    }

#define MATHG4(E0, E1, E2, E3, V0, V1, V2, V3, g)                          \
    {                                                                      \
        int _j = (g) * 4;                                                  \
        float p0 = __expf(fminf(lrelu(E0 + aldv), 60.f));                  \
        float p1 = (_j + 1 < deg) ? __expf(fminf(lrelu(E1 + aldv), 60.f)) : 0.f; \
        float p2 = (_j + 2 < deg) ? __expf(fminf(lrelu(E2 + aldv), 60.f)) : 0.f; \
        float p3 = (_j + 3 < deg) ? __expf(fminf(lrelu(E3 + aldv), 60.f)) : 0.f; \
        ssum += (p0 + p1) + (p2 + p3);                                     \
        _Pragma("unroll")                                                  \
        for (int k = 0; k < 8; k++)                                        \
            a[k] += (p0 * (float)V0[k] + p1 * (float)V1[k]) +              \
                    (p2 * (float)V2[k] + p3 * (float)V3[k]);               \
    }

__global__ __launch_bounds__(256) void k_agg4(const unsigned short* __restrict__ h16,
                                              const float* __restrict__ als,
                                              const float* __restrict__ ald,
                                              const int* __restrict__ cnt,
                                              const int* __restrict__ ell,
                                              const float* __restrict__ bias,
                                              unsigned short* __restrict__ xout,
                                              int n) {
    int gw = (blockIdx.x * blockDim.x + threadIdx.x) >> 6;
    int lane = threadIdx.x & 63;
    int wid = gw * 2 + (lane >> 5);
    if (wid >= n) return;
    int l = lane & 31;
    int head = l >> 3;       // 8 lanes per head
    int ch = l * 8;          // 8 f16 channels per lane
    int base = lane & 32;    // node-group base lane for shfl

    int deg = min(cnt[wid], WELL);
    const int* row = ell + (size_t)wid * WELL;
    int myid = (l < deg) ? row[l] : 0;   // cooperative id prefetch, slots 0..31

    float aldv = ald[wid * 4 + head];
    float p = __expf(fminf(lrelu(als[wid * 4 + head] + aldv), 60.f));
    float ssum = p;
    float a[8];
    {
        f16x8 h0 = *(const f16x8*)&h16[(size_t)wid * 256 + ch];
#pragma unroll
        for (int j = 0; j < 8; j++) a[j] = p * (float)h0[j];
    }

    int jmax = min(deg, 32);
    int dm1 = deg - 1;
    int G = (jmax + 3) >> 2;

    int sA0, sA1, sA2, sA3, sB0, sB1, sB2, sB3;
    float eA0, eA1, eA2, eA3, eB0, eB1, eB2, eB3;
    f16x8 vA0, vA1, vA2, vA3, vB0, vB1, vB2, vB3;

    if (G > 0) {
        LOADG4(sA0, sA1, sA2, sA3, eA0, eA1, eA2, eA3, vA0, vA1, vA2, vA3, 0);
        int g = 0;
        while (g + 2 <= G) {
            if (g + 1 < G)
                LOADG4(sB0, sB1, sB2, sB3, eB0, eB1, eB2, eB3, vB0, vB1, vB2, vB3, g + 1);
            MATHG4(eA0, eA1, eA2, eA3, vA0, vA1, vA2, vA3, g);
            if (g + 2 < G)
                LOADG4(sA0, sA1, sA2, sA3, eA0, eA1, eA2, eA3, vA0, vA1, vA2, vA3, g + 2);
            MATHG4(eB0, eB1, eB2, eB3, vB0, vB1, vB2, vB3, g + 1);
            g += 2;
        }
        if (g < G)
            MATHG4(eA0, eA1, eA2, eA3, vA0, vA1, vA2, vA3, g);
    }

    // rare tail: deg > 32
    for (int j = 32; j < deg; ++j) {
        int s0 = row[j];
        float p0 = __expf(fminf(lrelu(als[s0 * 4 + head] + aldv), 60.f));
        f16x8 v0 = *(const f16x8*)&h16[(size_t)s0 * 256 + ch];
        ssum += p0;
#pragma unroll
        for (int k = 0; k < 8; k++) a[k] += p0 * (float)v0[k];
    }

    float inv = 1.f / (ssum + 1e-16f);
    float bb[8];
    *(float4*)&bb[0] = *(const float4*)&bias[ch];
    *(float4*)&bb[4] = *(const float4*)&bias[ch + 4];
    unsigned short o[8];
#pragma unroll
    for (int k = 0; k < 8; k++) {
        float r = a[k] * inv + bb[k];
        r = r > 0.f ? r : expm1f(r);
        o[k] = f2b_rne(r);
    }
    *(int4*)&xout[(size_t)wid * 256 + ch] = *(const int4*)&o[0];
}

// ---- aggregation, H=1 C=64, final: 8 lanes/node, 8 ch/lane, f32 out -------
// Pipelined like k_agg4. Slots 0..7 via shfl; slots >=8 direct (L1) row[].
#define LOADG1(S0, S1, S2, S3, E0, E1, E2, E3, V0, V1, V2, V3, g)          \
    {                                                                      \
        int _j = (g) * 4;                                                  \
        if ((g) < 2) {                                                     \
            S0 = __shfl(myid, base + min(_j, dm1));                        \
            S1 = __shfl(myid, base + min(_j + 1, dm1));                    \
            S2 = __shfl(myid, base + min(_j + 2, dm1));                    \
            S3 = __shfl(myid, base + min(_j + 3, dm1));                    \
        } else {                                                           \
            S0 = row[min(_j, dm1)];                                        \
            S1 = row[min(_j + 1, dm1)];                                    \
            S2 = row[min(_j + 2, dm1)];                                    \
            S3 = row[min(_j + 3, dm1)];                                    \
        }                                                                  \
        E0 = als[S0]; E1 = als[S1]; E2 = als[S2]; E3 = als[S3];            \
        V0 = *(const f16x8*)&h16[(size_t)S0 * 64 + ch];                    \
        V1 = *(const f16x8*)&h16[(size_t)S1 * 64 + ch];                    \
        V2 = *(const f16x8*)&h16[(size_t)S2 * 64 + ch];                    \
        V3 = *(const f16x8*)&h16[(size_t)S3 * 64 + ch];                    \
    }

__global__ __launch_bounds__(256) void k_agg1(const unsigned short* __restrict__ h16,
                                              const float* __restrict__ als,
                                              const float* __restrict__ ald,
                                              const int* __restrict__ cnt,
                                              const int* __restrict__ ell,
                                              const float* __restrict__ bias,
                                              float* __restrict__ out, int n) {
    int gw = (blockIdx.x * blockDim.x + threadIdx.x) >> 6;
    int lane = threadIdx.x & 63;
    int wid = gw * 8 + (lane >> 3);
    if (wid >= n) return;
    int l = lane & 7;
    int ch = l * 8;
    int base = lane & 56;

    int deg = min(cnt[wid], WELL);
    const int* row = ell + (size_t)wid * WELL;
    int myid = (l < deg) ? row[l] : 0;

    float aldv = ald[wid];
    float p = __expf(fminf(lrelu(als[wid] + aldv), 60.f));
    float ssum = p;
    float a[8];
    {
        f16x8 hv = *(const f16x8*)&h16[(size_t)wid * 64 + ch];
#pragma unroll
        for (int k = 0; k < 8; k++) a[k] = p * (float)hv[k];
    }

    int dm1 = deg - 1;
    int G = (deg + 3) >> 2;

    int sA0, sA1, sA2, sA3, sB0, sB1, sB2, sB3;
    float eA0, eA1, eA2, eA3, eB0, eB1, eB2, eB3;
    f16x8 vA0, vA1, vA2, vA3, vB0, vB1, vB2, vB3;

    if (G > 0) {
        LOADG1(sA0, sA1, sA2, sA3, eA0, eA1, eA2, eA3, vA0, vA1, vA2, vA3, 0);
        int g = 0;
        while (g + 2 <= G) {
            if (g + 1 < G)
                LOADG1(sB0, sB1, sB2, sB3, eB0, eB1, eB2, eB3, vB0, vB1, vB2, vB3, g + 1);
            MATHG4(eA0, eA1, eA2, eA3, vA0, vA1, vA2, vA3, g);
            if (g + 2 < G)
                LOADG1(sA0, sA1, sA2, sA3, eA0, eA1, eA2, eA3, vA0, vA1, vA2, vA3, g + 2);
            MATHG4(eB0, eB1, eB2, eB3, vB0, vB1, vB2, vB3, g + 1);
            g += 2;
        }
        if (g < G)
            MATHG4(eA0, eA1, eA2, eA3, vA0, vA1, vA2, vA3, g);
    }

    float inv = 1.f / (ssum + 1e-16f);
    float bb[8];
    *(float4*)&bb[0] = *(const float4*)&bias[ch];
    *(float4*)&bb[4] = *(const float4*)&bias[ch + 4];
    float r[8];
#pragma unroll
    for (int k = 0; k < 8; k++) r[k] = a[k] * inv + bb[k];
    *(float4*)&out[(size_t)wid * 64 + ch] = *(const float4*)&r[0];
    *(float4*)&out[(size_t)wid * 64 + ch + 4] = *(const float4*)&r[4];
}

// ---------------------------------------------------------------------------
extern "C" void kernel_launch(void* const* d_in, const int* in_sizes, int n_in,
                              void* d_out, int out_size, void* d_ws, size_t ws_size,
                              hipStream_t stream) {
    const float* x   = (const float*)d_in[0];
    const int*   ei  = (const int*)d_in[1];
    const float* W1  = (const float*)d_in[2];
    const float* as1 = (const float*)d_in[3];
    const float* ad1 = (const float*)d_in[4];
    const float* b1  = (const float*)d_in[5];
    const float* W2  = (const float*)d_in[6];
    const float* as2 = (const float*)d_in[7];
    const float* ad2 = (const float*)d_in[8];
    const float* b2  = (const float*)d_in[9];
    const float* W3  = (const float*)d_in[10];
    const float* as3 = (const float*)d_in[11];
    const float* ad3 = (const float*)d_in[12];
    const float* b3  = (const float*)d_in[13];

    const int N = in_sizes[0] / 256;   // 50000
    const int E = in_sizes[1] / 2;     // 320000

    size_t off = 0;
    auto alloc = [&](size_t bytes) -> void* {
        void* p = (char*)d_ws + off;
        off += (bytes + 255) & ~(size_t)255;
        return p;
    };
    unsigned short* xb  = (unsigned short*)alloc((size_t)N * 256 * 2);
    unsigned short* W1t = (unsigned short*)alloc((size_t)256 * 256 * 2);
    unsigned short* W2t = (unsigned short*)alloc((size_t)256 * 256 * 2);
    unsigned short* W3t = (unsigned short*)alloc((size_t)64 * 256 * 2);
    unsigned short* h16 = (unsigned short*)alloc((size_t)N * 256 * 2);
    float* als = (float*)alloc((size_t)N * 4 * 4);
    float* ald = (float*)alloc((size_t)N * 4 * 4);
    int* cnt   = (int*)alloc((size_t)N * 4);
    int* ell   = (int*)alloc((size_t)N * WELL * 4);

    const int T = 256;
    const int agg4_blocks = (N + 7) / 8;    // 2 nodes/wave, 4 waves/block
    const int agg1_blocks = (N + 31) / 32;  // 8 nodes/wave, 4 waves/block
    const int mtiles = (N + 255) / 256;     // 196

    // init: zero cnt + W conversions (one launch)
    k_init<<<dim3(576), T, 0, stream>>>(W1, W2, W3, W1t, W2t, W3t, cnt, N);

    // layer 1 GEMM (A = x f32) + ELL fill on the 60 spare CUs
    k_gemm<16, true, true><<<dim3(mtiles + 60), 512, 0, stream>>>(
        x, (const __bf16*)W1t, h16, als, ald, as1, ad1, N, 4,
        ei, ei + E, cnt, ell, E, mtiles);
    k_agg4<<<dim3(agg4_blocks), T, 0, stream>>>(h16, als, ald, cnt, ell, b1, xb, N);

    // layer 2
    k_gemm<16, false, false><<<dim3(mtiles), 512, 0, stream>>>(
        xb, (const __bf16*)W2t, h16, als, ald, as2, ad2, N, 4,
        nullptr, nullptr, nullptr, nullptr, 0, mtiles);
    k_agg4<<<dim3(agg4_blocks), T, 0, stream>>>(h16, als, ald, cnt, ell, b2, xb, N);

    // layer 3 (H=1, C=64)
    k_gemm<4, false, false><<<dim3(mtiles), 512, 0, stream>>>(
        xb, (const __bf16*)W3t, h16, als, ald, as3, ad3, N, 1,
        nullptr, nullptr, nullptr, nullptr, 0, mtiles);
    k_agg1<<<dim3(agg1_blocks), T, 0, stream>>>(h16, als, ald, cnt, ell, b3,
                                                (float*)d_out, N);
}

// Round 8
// 252.423 us; speedup vs baseline: 1.0448x; 1.0149x over previous
//
#include <hip/hip_runtime.h>

// ---------------------------------------------------------------------------
// GAT 3-layer forward, MI355X (gfx950)
// R14: GEMM = R10b exactly (verified best). Agg = R9 lean bodies +
//      __launch_bounds__(256,8): cap 64 VGPR -> 8 waves/SIMD (2x occupancy).
//      Rationale: R13's deep gather pipelining was neutral (compiler already
//      hoists the 4 independent gathers); agg is TLP-starved, not ILP-starved
//      (fill kernel: 6.5 TB/s from trivial body + many waves).
// ---------------------------------------------------------------------------

typedef __attribute__((ext_vector_type(8))) __bf16 bf16x8;
typedef __attribute__((ext_vector_type(4))) float f32x4;
typedef _Float16 f16x8 __attribute__((ext_vector_type(8)));
typedef _Float16 f16x4 __attribute__((ext_vector_type(4)));

#define NEG_SLOPE 0.2f
#define WELL 40   // ELL row width; P(deg>40) ~ 1e-15 for E/N=6.4 Poisson

__device__ __forceinline__ unsigned short f2b_rne(float f) {
    unsigned int u = __float_as_uint(f);
    u += 0x7FFFu + ((u >> 16) & 1u);
    return (unsigned short)(u >> 16);
}
__device__ __forceinline__ unsigned short f2h(float f) {
    _Float16 h = (_Float16)f;
    unsigned short s;
    __builtin_memcpy(&s, &h, 2);
    return s;
}
__device__ __forceinline__ bf16x8 cvt8(const float* f) {
    unsigned short r[8];
#pragma unroll
    for (int j = 0; j < 8; j++) r[j] = f2b_rne(f[j]);
    bf16x8 v;
    __builtin_memcpy(&v, r, 16);
    return v;
}
__device__ __forceinline__ float lrelu(float e) {
    return e >= 0.f ? e : NEG_SLOPE * e;
}

// ---- init: zero cnt + all W -> Wt [Nout,256] bf16 transposed --------------
__global__ __launch_bounds__(256) void k_init(const float* __restrict__ W1,
                                              const float* __restrict__ W2,
                                              const float* __restrict__ W3,
                                              unsigned short* __restrict__ W1t,
                                              unsigned short* __restrict__ W2t,
                                              unsigned short* __restrict__ W3t,
                                              int* __restrict__ cnt, int n) {
    int t = blockIdx.x * blockDim.x + threadIdx.x;
    if (t < n) cnt[t] = 0;
    const float* W;
    unsigned short* Wt;
    int Nout, idx = t;
    if (idx < 65536)        { W = W1; Wt = W1t; Nout = 256; }
    else if (idx < 131072)  { W = W2; Wt = W2t; Nout = 256; idx -= 65536; }
    else if (idx < 147456)  { W = W3; Wt = W3t; Nout = 64;  idx -= 131072; }
    else return;
    int k = idx / Nout;
    int c = idx - k * Nout;
    Wt[(size_t)c * 256 + k] = f2b_rne(W[idx]);
}

// ---- GEMM (R10b): h16[M,NT*16] f16 = A[M,256] @ Wt[NT*16,256]^T -----------
// Whole B-slab in LDS (NT*16 x 256 bf16), XOR chunk swizzle, staged once.
// Each wave: 32 rows, whole K in VGPRs, NT*16 cols, barrier-free K-loop.
// A loads issued AFTER the staging barrier. 512 thr = 8 waves = 256 rows.
template <int NT, bool AF32, bool FILL>
__global__ __launch_bounds__(512) void k_gemm(const void* __restrict__ Av,
                                              const __bf16* __restrict__ Bt,
                                              unsigned short* __restrict__ h16,
                                              float* __restrict__ als,
                                              float* __restrict__ ald,
                                              const float* __restrict__ a_s,
                                              const float* __restrict__ a_d,
                                              int M, int H,
                                              const int* __restrict__ esrc,
                                              const int* __restrict__ edst,
                                              int* __restrict__ cnt,
                                              int* __restrict__ ell,
                                              int E, int mtiles) {
    constexpr int NN = NT * 16;
    __shared__ __align__(16) __bf16 Bs[NN][256];

    if (FILL && (int)blockIdx.x >= mtiles) {
        int t = ((int)blockIdx.x - mtiles) * (int)blockDim.x + (int)threadIdx.x;
        int stride = ((int)gridDim.x - mtiles) * (int)blockDim.x;
        for (; t < E; t += stride) {
            int d = edst[t];
            int pos = atomicAdd(&cnt[d], 1);
            if (pos < WELL) ell[(size_t)d * WELL + pos] = esrc[t];
        }
        return;
    }

    const int tid = threadIdx.x;
    const int lane = tid & 63;
    const int w = tid >> 6;          // 8 waves
    const int i = lane & 15;
    const int quad = lane >> 4;
    const int m0 = blockIdx.x * 256;

    // ---- stage B slab once; chunk p of row n holds global chunk p^(n&7) ---
    {
        int nl = lane >> 5;          // 0..1
        int p = lane & 31;
#pragma unroll
        for (int t = 0; t < NN / 16; t++) {
            int n = t * 16 + w * 2 + nl;
            int g = p ^ (n & 7);
            const __bf16* gp = Bt + (size_t)n * 256 + g * 8;
            __builtin_amdgcn_global_load_lds(
                (const __attribute__((address_space(1))) void*)gp,
                (__attribute__((address_space(3))) void*)&Bs[t * 16 + w * 2][0],
                16, 0, 0);
        }
    }

    int ra = m0 + w * 32 + i;
    int rb = ra + 16;
    if (ra >= M) ra = M - 1;
    if (rb >= M) rb = M - 1;

    f32x4 acc[2][NT] = {};
    bf16x8 afrag[2][8];   // [strip][kc]

    __syncthreads();   // drains ONLY B staging; A loads issued below

    if (AF32) {
        const float* pa = (const float*)Av + (size_t)ra * 256;
        const float* pb = (const float*)Av + (size_t)rb * 256;
        float tmp[2][4][8];
        // half 0 loads: K 0..127
#pragma unroll
        for (int k4 = 0; k4 < 4; k4++) {
            int koff = k4 * 32 + quad * 8;
            *(float4*)&tmp[0][k4][0] = *(const float4*)(pa + koff);
            *(float4*)&tmp[0][k4][4] = *(const float4*)(pa + koff + 4);
            *(float4*)&tmp[1][k4][0] = *(const float4*)(pb + koff);
            *(float4*)&tmp[1][k4][4] = *(const float4*)(pb + koff + 4);
        }
#pragma unroll
        for (int k4 = 0; k4 < 4; k4++) {
            afrag[0][k4] = cvt8(tmp[0][k4]);
            afrag[1][k4] = cvt8(tmp[1][k4]);
        }
        // half 1 loads (reuse tmp) in flight while MFMA kc 0..3 runs
#pragma unroll
        for (int k4 = 0; k4 < 4; k4++) {
            int koff = (4 + k4) * 32 + quad * 8;
            *(float4*)&tmp[0][k4][0] = *(const float4*)(pa + koff);
            *(float4*)&tmp[0][k4][4] = *(const float4*)(pa + koff + 4);
            *(float4*)&tmp[1][k4][0] = *(const float4*)(pb + koff);
            *(float4*)&tmp[1][k4][4] = *(const float4*)(pb + koff + 4);
        }
#pragma unroll
        for (int kc = 0; kc < 4; kc++) {
            const int c = kc * 4 + quad;
#pragma unroll
            for (int nt = 0; nt < NT; nt++) {
                const int n = nt * 16 + i;
                const int p = c ^ (n & 7);
                bf16x8 bfv = *(const bf16x8*)&Bs[n][p * 8];
                acc[0][nt] = __builtin_amdgcn_mfma_f32_16x16x32_bf16(
                    afrag[0][kc], bfv, acc[0][nt], 0, 0, 0);
                acc[1][nt] = __builtin_amdgcn_mfma_f32_16x16x32_bf16(
                    afrag[1][kc], bfv, acc[1][nt], 0, 0, 0);
            }
        }
#pragma unroll
        for (int k4 = 0; k4 < 4; k4++) {
            afrag[0][4 + k4] = cvt8(tmp[0][k4]);
            afrag[1][4 + k4] = cvt8(tmp[1][k4]);
        }
#pragma unroll
        for (int kc = 4; kc < 8; kc++) {
            const int c = kc * 4 + quad;
#pragma unroll
            for (int nt = 0; nt < NT; nt++) {
                const int n = nt * 16 + i;
                const int p = c ^ (n & 7);
                bf16x8 bfv = *(const bf16x8*)&Bs[n][p * 8];
                acc[0][nt] = __builtin_amdgcn_mfma_f32_16x16x32_bf16(
                    afrag[0][kc], bfv, acc[0][nt], 0, 0, 0);
                acc[1][nt] = __builtin_amdgcn_mfma_f32_16x16x32_bf16(
                    afrag[1][kc], bfv, acc[1][nt], 0, 0, 0);
            }
        }
    } else {
        const __bf16* pa = (const __bf16*)Av + (size_t)ra * 256;
        const __bf16* pb = (const __bf16*)Av + (size_t)rb * 256;
#pragma unroll
        for (int kc = 0; kc < 8; kc++) {
            int koff = kc * 32 + quad * 8;
            afrag[0][kc] = *(const bf16x8*)(pa + koff);
            afrag[1][kc] = *(const bf16x8*)(pb + koff);
        }
#pragma unroll
        for (int kc = 0; kc < 8; kc++) {
            const int c = kc * 4 + quad;
#pragma unroll
            for (int nt = 0; nt < NT; nt++) {
                const int n = nt * 16 + i;
                const int p = c ^ (n & 7);
                bf16x8 bfv = *(const bf16x8*)&Bs[n][p * 8];
                acc[0][nt] = __builtin_amdgcn_mfma_f32_16x16x32_bf16(
                    afrag[0][kc], bfv, acc[0][nt], 0, 0, 0);
                acc[1][nt] = __builtin_amdgcn_mfma_f32_16x16x32_bf16(
                    afrag[1][kc], bfv, acc[1][nt], 0, 0, 0);
            }
        }
    }

    // ---- epilogue: C/D map col=lane&15, row=quad*4+reg --------------------
    float asv[NT], adv[NT];
#pragma unroll
    for (int nt = 0; nt < NT; nt++) {
        asv[nt] = a_s[(nt / 4) * 64 + (nt & 3) * 16 + i];
        adv[nt] = a_d[(nt / 4) * 64 + (nt & 3) * 16 + i];
    }

#pragma unroll
    for (int mt = 0; mt < 2; mt++) {
#pragma unroll
        for (int r = 0; r < 4; r++) {
            int row = m0 + w * 32 + mt * 16 + quad * 4 + r;
            bool ok = row < M;
#pragma unroll
            for (int nt = 0; nt < NT; nt++) {
                if (ok) h16[(size_t)row * NN + nt * 16 + i] = f2h(acc[mt][nt][r]);
            }
#pragma unroll
            for (int g = 0; g < (NT + 3) / 4; g++) {
                float ps = 0.f, pd = 0.f;
#pragma unroll
                for (int j = 0; j < 4 && g * 4 + j < NT; j++) {
                    float v = acc[mt][g * 4 + j][r];
                    ps += v * asv[g * 4 + j];
                    pd += v * adv[g * 4 + j];
                }
#pragma unroll
                for (int off = 1; off <= 8; off <<= 1) {
                    ps += __shfl_xor(ps, off, 64);
                    pd += __shfl_xor(pd, off, 64);
                }
                if (ok && i == 0) {
                    als[(size_t)row * H + g] = ps;
                    ald[(size_t)row * H + g] = pd;
                }
            }
        }
    }
}

// ---- aggregation, H=4 C=64: 2 nodes/wave, 32 lanes/node, 8 ch/lane --------
// R9 lean body; __launch_bounds__(256,8) caps 64 VGPR -> 8 waves/SIMD.
__global__ __launch_bounds__(256, 8) void k_agg4(const unsigned short* __restrict__ h16,
                                              const float* __restrict__ als,
                                              const float* __restrict__ ald,
                                              const int* __restrict__ cnt,
                                              const int* __restrict__ ell,
                                              const float* __restrict__ bias,
                                              unsigned short* __restrict__ xout,
                                              int n) {
    int gw = (blockIdx.x * blockDim.x + threadIdx.x) >> 6;
    int lane = threadIdx.x & 63;
    int wid = gw * 2 + (lane >> 5);
    if (wid >= n) return;
    int l = lane & 31;
    int head = l >> 3;       // 8 lanes per head
    int ch = l * 8;          // 8 f16 channels per lane
    int base = lane & 32;    // node-group base lane for shfl

    int deg = min(cnt[wid], WELL);
    const int* row = ell + (size_t)wid * WELL;
    int myid = (l < deg) ? row[l] : 0;   // cooperative id prefetch, slots 0..31

    float aldv = ald[wid * 4 + head];
    float p = __expf(fminf(lrelu(als[wid * 4 + head] + aldv), 60.f));
    float ssum = p;
    float a[8];
    {
        f16x8 h0 = *(const f16x8*)&h16[(size_t)wid * 256 + ch];
#pragma unroll
        for (int j = 0; j < 8; j++) a[j] = p * (float)h0[j];
    }

    int jmax = min(deg, 32);
    int dm1 = deg - 1;
    for (int j = 0; j < jmax; j += 4) {
        int s0 = __shfl(myid, base + min(j, dm1));
        int s1 = __shfl(myid, base + min(j + 1, dm1));
        int s2 = __shfl(myid, base + min(j + 2, dm1));
        int s3 = __shfl(myid, base + min(j + 3, dm1));
        float e0 = als[s0 * 4 + head];
        float e1 = als[s1 * 4 + head];
        float e2 = als[s2 * 4 + head];
        float e3 = als[s3 * 4 + head];
        f16x8 v0 = *(const f16x8*)&h16[(size_t)s0 * 256 + ch];
        f16x8 v1 = *(const f16x8*)&h16[(size_t)s1 * 256 + ch];
        f16x8 v2 = *(const f16x8*)&h16[(size_t)s2 * 256 + ch];
        f16x8 v3 = *(const f16x8*)&h16[(size_t)s3 * 256 + ch];
        float p0 = __expf(fminf(lrelu(e0 + aldv), 60.f));
        float p1 = (j + 1 < deg) ? __expf(fminf(lrelu(e1 + aldv), 60.f)) : 0.f;
        float p2 = (j + 2 < deg) ? __expf(fminf(lrelu(e2 + aldv), 60.f)) : 0.f;
        float p3 = (j + 3 < deg) ? __expf(fminf(lrelu(e3 + aldv), 60.f)) : 0.f;
        ssum += (p0 + p1) + (p2 + p3);
#pragma unroll
        for (int k = 0; k < 8; k++) {
            a[k] += (p0 * (float)v0[k] + p1 * (float)v1[k]) +
                    (p2 * (float)v2[k] + p3 * (float)v3[k]);
        }
    }
    // rare tail: deg > 32
    for (int j = 32; j < deg; ++j) {
        int s0 = row[j];
        float p0 = __expf(fminf(lrelu(als[s0 * 4 + head] + aldv), 60.f));
        f16x8 v0 = *(const f16x8*)&h16[(size_t)s0 * 256 + ch];
        ssum += p0;
#pragma unroll
        for (int k = 0; k < 8; k++) a[k] += p0 * (float)v0[k];
    }

    float inv = 1.f / (ssum + 1e-16f);
    float bb[8];
    *(float4*)&bb[0] = *(const float4*)&bias[ch];
    *(float4*)&bb[4] = *(const float4*)&bias[ch + 4];
    unsigned short o[8];
#pragma unroll
    for (int k = 0; k < 8; k++) {
        float r = a[k] * inv + bb[k];
        r = r > 0.f ? r : expm1f(r);
        o[k] = f2b_rne(r);
    }
    *(int4*)&xout[(size_t)wid * 256 + ch] = *(const int4*)&o[0];
}

// ---- aggregation, H=1 C=64, final: 8 lanes/node, 8 ch/lane, f32 out -------
// R9 lean body; __launch_bounds__(256,8) caps 64 VGPR -> 8 waves/SIMD.
__global__ __launch_bounds__(256, 8) void k_agg1(const unsigned short* __restrict__ h16,
                                              const float* __restrict__ als,
                                              const float* __restrict__ ald,
                                              const int* __restrict__ cnt,
                                              const int* __restrict__ ell,
                                              const float* __restrict__ bias,
                                              float* __restrict__ out, int n) {
    int gw = (blockIdx.x * blockDim.x + threadIdx.x) >> 6;
    int lane = threadIdx.x & 63;
    int wid = gw * 8 + (lane >> 3);
    if (wid >= n) return;
    int l = lane & 7;
    int ch = l * 8;
    int base = lane & 56;

    int deg = min(cnt[wid], WELL);
    const int* row = ell + (size_t)wid * WELL;
    int myid = (l < deg) ? row[l] : 0;

    float aldv = ald[wid];
    float p = __expf(fminf(lrelu(als[wid] + aldv), 60.f));
    float ssum = p;
    float a[8];
    {
        f16x8 hv = *(const f16x8*)&h16[(size_t)wid * 64 + ch];
#pragma unroll
        for (int k = 0; k < 8; k++) a[k] = p * (float)hv[k];
    }

    int dm1 = deg - 1;
    for (int j = 0; j < deg; j += 4) {
        int i0 = min(j, dm1), i1 = min(j + 1, dm1);
        int i2 = min(j + 2, dm1), i3 = min(j + 3, dm1);
        int s0, s1, s2, s3;
        if (j < 8) {
            s0 = __shfl(myid, base + i0);
            s1 = __shfl(myid, base + i1);
            s2 = __shfl(myid, base + i2);
            s3 = __shfl(myid, base + i3);
        } else {
            s0 = row[i0]; s1 = row[i1]; s2 = row[i2]; s3 = row[i3];
        }
        float e0 = als[s0], e1 = als[s1], e2 = als[s2], e3 = als[s3];
        f16x8 v0 = *(const f16x8*)&h16[(size_t)s0 * 64 + ch];
        f16x8 v1 = *(const f16x8*)&h16[(size_t)s1 * 64 + ch];
        f16x8 v2 = *(const f16x8*)&h16[(size_t)s2 * 64 + ch];
        f16x8 v3 = *(const f16x8*)&h16[(size_t)s3 * 64 + ch];
        float p0 = __expf(fminf(lrelu(e0 + aldv), 60.f));
        float p1 = (j + 1 < deg) ? __expf(fminf(lrelu(e1 + aldv), 60.f)) : 0.f;
        float p2 = (j + 2 < deg) ? __expf(fminf(lrelu(e2 + aldv), 60.f)) : 0.f;
        float p3 = (j + 3 < deg) ? __expf(fminf(lrelu(e3 + aldv), 60.f)) : 0.f;
        ssum += (p0 + p1) + (p2 + p3);
#pragma unroll
        for (int k = 0; k < 8; k++)
            a[k] += (p0 * (float)v0[k] + p1 * (float)v1[k]) +
                    (p2 * (float)v2[k] + p3 * (float)v3[k]);
    }

    float inv = 1.f / (ssum + 1e-16f);
    float bb[8];
    *(float4*)&bb[0] = *(const float4*)&bias[ch];
    *(float4*)&bb[4] = *(const float4*)&bias[ch + 4];
    float r[8];
#pragma unroll
    for (int k = 0; k < 8; k++) r[k] = a[k] * inv + bb[k];
    *(float4*)&out[(size_t)wid * 64 + ch] = *(const float4*)&r[0];
    *(float4*)&out[(size_t)wid * 64 + ch + 4] = *(const float4*)&r[4];
}

// ---------------------------------------------------------------------------
extern "C" void kernel_launch(void* const* d_in, const int* in_sizes, int n_in,
                              void* d_out, int out_size, void* d_ws, size_t ws_size,
                              hipStream_t stream) {
    const float* x   = (const float*)d_in[0];
    const int*   ei  = (const int*)d_in[1];
    const float* W1  = (const float*)d_in[2];
    const float* as1 = (const float*)d_in[3];
    const float* ad1 = (const float*)d_in[4];
    const float* b1  = (const float*)d_in[5];
    const float* W2  = (const float*)d_in[6];
    const float* as2 = (const float*)d_in[7];
    const float* ad2 = (const float*)d_in[8];
    const float* b2  = (const float*)d_in[9];
    const float* W3  = (const float*)d_in[10];
    const float* as3 = (const float*)d_in[11];
    const float* ad3 = (const float*)d_in[12];
    const float* b3  = (const float*)d_in[13];

    const int N = in_sizes[0] / 256;   // 50000
    const int E = in_sizes[1] / 2;     // 320000

    size_t off = 0;
    auto alloc = [&](size_t bytes) -> void* {
        void* p = (char*)d_ws + off;
        off += (bytes + 255) & ~(size_t)255;
        return p;
    };
    unsigned short* xb  = (unsigned short*)alloc((size_t)N * 256 * 2);
    unsigned short* W1t = (unsigned short*)alloc((size_t)256 * 256 * 2);
    unsigned short* W2t = (unsigned short*)alloc((size_t)256 * 256 * 2);
    unsigned short* W3t = (unsigned short*)alloc((size_t)64 * 256 * 2);
    unsigned short* h16 = (unsigned short*)alloc((size_t)N * 256 * 2);
    float* als = (float*)alloc((size_t)N * 4 * 4);
    float* ald = (float*)alloc((size_t)N * 4 * 4);
    int* cnt   = (int*)alloc((size_t)N * 4);
    int* ell   = (int*)alloc((size_t)N * WELL * 4);

    const int T = 256;
    const int agg4_blocks = (N + 7) / 8;    // 2 nodes/wave, 4 waves/block
    const int agg1_blocks = (N + 31) / 32;  // 8 nodes/wave, 4 waves/block
    const int mtiles = (N + 255) / 256;     // 196

    // init: zero cnt + W conversions (one launch)
    k_init<<<dim3(576), T, 0, stream>>>(W1, W2, W3, W1t, W2t, W3t, cnt, N);

    // layer 1 GEMM (A = x f32) + ELL fill on the 60 spare CUs
    k_gemm<16, true, true><<<dim3(mtiles + 60), 512, 0, stream>>>(
        x, (const __bf16*)W1t, h16, als, ald, as1, ad1, N, 4,
        ei, ei + E, cnt, ell, E, mtiles);
    k_agg4<<<dim3(agg4_blocks), T, 0, stream>>>(h16, als, ald, cnt, ell, b1, xb, N);

    // layer 2
    k_gemm<16, false, false><<<dim3(mtiles), 512, 0, stream>>>(
        xb, (const __bf16*)W2t, h16, als, ald, as2, ad2, N, 4,
        nullptr, nullptr, nullptr, nullptr, 0, mtiles);
    k_agg4<<<dim3(agg4_blocks), T, 0, stream>>>(h16, als, ald, cnt, ell, b2, xb, N);

    // layer 3 (H=1, C=64)
    k_gemm<4, false, false><<<dim3(mtiles), 512, 0, stream>>>(
        xb, (const __bf16*)W3t, h16, als, ald, as3, ad3, N, 1,
        nullptr, nullptr, nullptr, nullptr, 0, mtiles);
    k_agg1<<<dim3(agg1_blocks), T, 0, stream>>>(h16, als, ald, cnt, ell, b3,
                                                (float*)d_out, N);
}